// Round 20
// baseline (273.687 us; speedup 1.0000x reference)
//
#include <hip/hip_runtime.h>

typedef unsigned int u32;
typedef __attribute__((ext_vector_type(8))) short short8;
typedef __attribute__((ext_vector_type(4))) short short4v;
typedef __attribute__((ext_vector_type(2))) u32 u32x2;
typedef __attribute__((ext_vector_type(4))) float f32x4;

#define DM 512
#define NH 8
#define DK 64
#define NF 256
#define L_ 8192
#define SCALE 0.35355339059327373f   // 64^-0.25
#define INVSQM 0.0625f               // 256^-0.5
#define EPS_ 1e-6f

__device__ __forceinline__ float bf2f(short s){
  union { u32 u; float f; } x; x.u = ((u32)(unsigned short)s) << 16; return x.f;
}
__device__ __forceinline__ short f2bf(float f){
  union { float f; u32 u; } x; x.f = f;
  u32 r = (x.u + 0x7FFF + ((x.u >> 16) & 1)) >> 16;
  return (short)r;
}
// HW packed convert: 2 fp32 -> 2 bf16 (RTNE) in one VALU op [T12 recipe]
__device__ __forceinline__ u32 cvtpk(float lo, float hi){
  u32 r;
  asm("v_cvt_pk_bf16_f32 %0, %1, %2" : "=v"(r) : "v"(lo), "v"(hi));
  return r;
}

typedef const __attribute__((address_space(1))) u32* gas_t;
typedef __attribute__((address_space(3))) u32* las_t;
__device__ __forceinline__ void gl_lds16(const void* g, void* l){
  __builtin_amdgcn_global_load_lds((gas_t)g, (las_t)l, 16, 0, 0);
}
__device__ __forceinline__ f32x4 mfma16(short8 a, short8 b, f32x4 c){
  return __builtin_amdgcn_mfma_f32_16x16x32_bf16(a, b, c, 0, 0, 0);
}
__device__ __forceinline__ short8 lds_read8(const void* base, int byteoff){
  return *reinterpret_cast<const short8*>((const char*)base + byteoff);
}

// ---------------- transpose 4 fp32 weight matrices -> bf16 Wt[n][k] = W[k][n] ----------------
__global__ __launch_bounds__(256) void k_wt(const float* __restrict__ W0, const float* __restrict__ W1,
                                            const float* __restrict__ W2, const float* __restrict__ W3,
                                            short* __restrict__ Wt){
  int bid = blockIdx.x;              // 4 mats x 64 tiles
  int mat = bid >> 6;
  int tr = (bid >> 3) & 7, tc = bid & 7;
  const float* W = mat==0 ? W0 : mat==1 ? W1 : mat==2 ? W2 : W3;
  short* O = Wt + (size_t)mat*DM*DM;
  __shared__ __align__(16) short tl[64*72];   // rows 144B
  int t = threadIdx.x;
  #pragma unroll
  for (int i=0;i<4;++i){
    int c = i*256 + t;               // 1024 chunks of 4 floats
    int r = c >> 4, cc = c & 15;
    f32x4 v = *reinterpret_cast<const f32x4*>(W + (size_t)(tr*64+r)*DM + tc*64 + cc*4);
    u32x2 o; o[0] = cvtpk(v[0], v[1]); o[1] = cvtpk(v[2], v[3]);
    *reinterpret_cast<u32x2*>((char*)tl + r*144 + cc*8) = o;
  }
  __syncthreads();
  #pragma unroll
  for (int i=0;i<2;++i){
    int c = i*256 + t;
    int n = c >> 3, kc = c & 7;
    short8 v;
    #pragma unroll
    for (int q=0;q<8;++q) v[q] = tl[(kc*8+q)*72 + n];
    *reinterpret_cast<short8*>(O + (size_t)(tc*64+n)*DM + tr*64 + kc*8) = v;
  }
}

// ---------------- omega fp32 -> canonical bf16 ----------------
__global__ __launch_bounds__(256) void k_omc(const float* __restrict__ Om, short* __restrict__ omc){
  int i = blockIdx.x*256 + threadIdx.x;
  f32x4 v = *((const f32x4*)Om + i);
  u32x2 o; o[0] = cvtpk(v[0], v[1]); o[1] = cvtpk(v[2], v[3]);
  *((u32x2*)omc + i) = o;
}

// ---------------- merged QKV projection GEMM, BN-PAIRED: one A-stage feeds 2 col-tiles ----------
// grid (nbm*2, 3). y=0: Q -> qh; y=1: K -> kh; y=2: V -> vT.
// LDS: lA 16KB + lB 32KB (256 rows); lC aliases lB. A staged/converted ONCE per 256 output cols.
__global__ __launch_bounds__(256) void k_gemm3(const float* __restrict__ Q, const float* __restrict__ K,
                                               const float* __restrict__ V, const short* __restrict__ wt,
                                               short* __restrict__ qh, short* __restrict__ kh,
                                               short* __restrict__ vT, int rbase){
  __shared__ __align__(16) char smem[51200];
  short* lA = (short*)smem;                    // 16384 B (128 rows x 128B)
  short* lB = (short*)(smem + 16384);          // 32768 B (256 rows x 128B)
  short* lC = (short*)(smem + 16384);          // 34816 B alias (epilogue only)
  const int mode = blockIdx.y;
  const float* A = mode==0 ? Q : mode==1 ? K : V;
  const short* Bt = wt + (size_t)mode*DM*DM;
  const int t = threadIdx.x;
  const int w = t >> 6, lane = t & 63;
  const int wr = w >> 1, wc = w & 1;
  // XCD swizzle: the 2 blocks sharing an A-panel land on the same XCD.
  const int bid = blockIdx.x;
  const int bmx = gridDim.x >> 4;          // bm tiles per XCD (grid/8/2)
  const int j = bid >> 3;
  const int bm = (bid & 7)*bmx + (j >> 1);
  const int bnp = j & 1;
  const int row0 = bm*128, n0 = bnp*256;
  f32x4 acc[2][4][4] = {};
  for (int ks=0; ks<8; ++ks){
    const float* gA32 = A + (size_t)(rbase+row0)*DM + ks*64;
    #pragma unroll
    for (int rnd=0; rnd<8; ++rnd){
      int c = rnd*256 + t;
      int r = c >> 4, cc = c & 15;
      f32x4 v = *reinterpret_cast<const f32x4*>(gA32 + (size_t)r*DM + cc*4);
      u32x2 o; o[0] = cvtpk(v[0], v[1]); o[1] = cvtpk(v[2], v[3]);
      int po = cc*8;
      *reinterpret_cast<u32x2*>((char*)lA + r*128 + (po ^ ((r&7)<<4))) = o;
    }
    const char* gB = (const char*)(Bt + (size_t)n0*DM + ks*64);
    #pragma unroll
    for (int rnd=0; rnd<8; ++rnd){
      int d = (rnd*256 + t)*16;
      int r = d >> 7, po = d & 127;
      gl_lds16(gB + (size_t)r*(DM*2) + (po ^ ((r&7)<<4)), (char*)lB + rnd*4096 + w*1024);
    }
    __syncthreads();
    #pragma unroll
    for (int kk=0; kk<2; ++kk){
      int kb = (kk*32 + ((lane>>4)<<3))*2;
      short8 af[4];
      #pragma unroll
      for (int i=0;i<4;++i){
        int m = wr*64 + i*16 + (lane&15);
        af[i] = lds_read8(lA, m*128 + (kb ^ ((m&7)<<4)));
      }
      #pragma unroll
      for (int h=0;h<2;++h){
        short8 bfr[4];
        #pragma unroll
        for (int j2=0;j2<4;++j2){
          int n = h*128 + wc*64 + j2*16 + (lane&15);
          bfr[j2] = lds_read8(lB, n*128 + (kb ^ ((n&7)<<4)));
        }
        #pragma unroll
        for (int i=0;i<4;++i)
          #pragma unroll
          for (int j2=0;j2<4;++j2)
            acc[h][i][j2] = mfma16(af[i], bfr[j2], acc[h][i][j2]);
      }
    }
    __syncthreads();
  }
  const int b = row0 >> 13;
  const int l0 = row0 & 8191;
  #pragma unroll
  for (int h=0;h<2;++h){
    #pragma unroll
    for (int i=0;i<4;++i)
      #pragma unroll
      for (int j2=0;j2<4;++j2)
        #pragma unroll
        for (int jj=0;jj<4;++jj){
          int row = wr*64 + i*16 + ((lane>>4)<<2) + jj;
          int col = wc*64 + j2*16 + (lane&15);
          lC[row*136 + col] = f2bf(acc[h][i][j2][jj]);
        }
    __syncthreads();
    const int colbase = n0 + h*128;
    if (mode < 2){
      short* Os = mode ? kh : qh;
      #pragma unroll
      for (int it=0; it<8; ++it){
        int p = it*256 + t;
        int row = p >> 4, c16 = p & 15;
        short8 v = *reinterpret_cast<const short8*>((char*)lC + row*272 + c16*16);
        int col0 = colbase + c16*8;
        int hh = col0 >> 6, dv = col0 & 63;
        size_t off = ((size_t)(b*NH + hh)*L_ + (l0+row))*DK + dv;
        *reinterpret_cast<short8*>(Os + off) = v;
      }
    } else {
      #pragma unroll
      for (int it=0; it<8; ++it){
        int p = it*256 + t;
        int col = p >> 4, lp = p & 15;
        short8 v;
        #pragma unroll
        for (int q=0;q<8;++q) v[q] = lC[(lp*8+q)*136 + col];
        int ac = colbase + col;
        int hh = ac >> 6, dv = ac & 63;
        size_t off = ((size_t)(b*NH+hh)*DK + dv)*L_ + l0 + lp*8;
        *reinterpret_cast<short8*>(vT + off) = v;
      }
    }
    __syncthreads();
  }
}

// ---------------- output GEMM (r16 config): attn bf16 x WoT -> fp32 d_out ----------------
__global__ __launch_bounds__(256) void k_gemmO(const short* __restrict__ A, const short* __restrict__ Bt,
                                               float* __restrict__ Out, int rbase){
  __shared__ __align__(16) short lA[128*64];
  __shared__ __align__(16) short lB[128*64];
  const int t = threadIdx.x;
  const int w = t >> 6, lane = t & 63;
  const int wr = w >> 1, wc = w & 1;
  const int bid = blockIdx.x;
  const int bmx = gridDim.x >> 5;
  const int j = bid >> 3;
  const int bm = (bid & 7)*bmx + (j >> 2);
  const int bn = j & 3;
  const int row0 = bm*128, n0 = bn*128;
  f32x4 acc[4][4] = {};
  for (int ks=0; ks<8; ++ks){
    const char* gA = (const char*)(A + (size_t)(rbase+row0)*DM + ks*64);
    #pragma unroll
    for (int rnd=0; rnd<4; ++rnd){
      int d = (rnd*256 + t)*16;
      int r = d >> 7, po = d & 127;
      gl_lds16(gA + (size_t)r*(DM*2) + (po ^ ((r&7)<<4)), (char*)lA + rnd*4096 + w*1024);
    }
    const char* gB = (const char*)(Bt + (size_t)n0*DM + ks*64);
    #pragma unroll
    for (int rnd=0; rnd<4; ++rnd){
      int d = (rnd*256 + t)*16;
      int r = d >> 7, po = d & 127;
      gl_lds16(gB + (size_t)r*(DM*2) + (po ^ ((r&7)<<4)), (char*)lB + rnd*4096 + w*1024);
    }
    __syncthreads();
    #pragma unroll
    for (int kk=0; kk<2; ++kk){
      int kb = (kk*32 + ((lane>>4)<<3))*2;
      short8 af[4], bfr[4];
      #pragma unroll
      for (int i=0;i<4;++i){
        int m = wr*64 + i*16 + (lane&15);
        af[i] = lds_read8(lA, m*128 + (kb ^ ((m&7)<<4)));
      }
      #pragma unroll
      for (int j2=0;j2<4;++j2){
        int n = wc*64 + j2*16 + (lane&15);
        bfr[j2] = lds_read8(lB, n*128 + (kb ^ ((n&7)<<4)));
      }
      #pragma unroll
      for (int i=0;i<4;++i)
        #pragma unroll
        for (int j2=0;j2<4;++j2)
          acc[i][j2] = mfma16(af[i], bfr[j2], acc[i][j2]);
    }
    __syncthreads();
  }
  #pragma unroll
  for (int i=0;i<4;++i)
    #pragma unroll
    for (int j2=0;j2<4;++j2)
      #pragma unroll
      for (int jj=0;jj<4;++jj){
        int row = wr*64 + i*16 + ((lane>>4)<<2) + jj;
        int col = wc*64 + j2*16 + (lane&15);
        Out[(size_t)(row0+row)*DM + n0 + col] = acc[i][j2][jj];
      }
}

// ---------------- phi(k) r7 + swizzled LDS (lOm/lK/lV); lP padded-linear ----------------
// grid = nbh*8 (bh*8+split); 512 threads; each split: 1024 rows = 8 chunks of 128
__global__ __launch_bounds__(512) void k_phik(const short* __restrict__ kh, const short* __restrict__ vT,
                                              const short* __restrict__ omega,
                                              float* __restrict__ kvp, float* __restrict__ ksp){
  __shared__ __align__(16) short lOm[256*64];
  __shared__ __align__(16) short lK[128*64];
  __shared__ __align__(16) short lV[64*128];
  __shared__ __align__(16) short lP[256*136];
  __shared__ float lSq[128];
  __shared__ float lKsP[8][256];
  const int t = threadIdx.x, w = t>>6, lane = t&63;
  const int bid = blockIdx.x;
  const int bh = bid >> 3, sp = bid & 7;
  const char* khb = (const char*)(kh + (size_t)bh*L_*DK);
  const char* vtb = (const char*)(vT + (size_t)bh*DK*L_);
  #pragma unroll
  for (int rnd=0; rnd<4; ++rnd){
    int d = (rnd*512 + t)*16;
    int r = d >> 7, po = d & 127;
    gl_lds16((const char*)omega + r*128 + (po ^ ((r&7)<<4)), (char*)lOm + rnd*8192 + w*1024);
  }
  f32x4 kv[4][2] = {};
  float ksa[16] = {};
  for (int c=0;c<8;++c){
    int l0 = sp*1024 + c*128;
    #pragma unroll
    for (int rnd=0; rnd<2; ++rnd){
      int d = (rnd*512 + t)*16;
      { int r = d>>7, po = d&127;
        gl_lds16(khb + (size_t)(l0+r)*128 + (po ^ ((r&7)<<4)), (char*)lK + rnd*8192 + w*1024); }
      { int r = d>>8, po = d&255;
        gl_lds16(vtb + (size_t)r*(L_*2) + (size_t)l0*2 + (po ^ ((r&15)<<4)), (char*)lV + rnd*8192 + w*1024); }
    }
    __syncthreads();
    {
      int row = t >> 2, part = t & 3;
      float ss = 0.f;
      #pragma unroll
      for (int hh=0; hh<2; ++hh){
        int cb = part*32 + hh*16;
        short8 v = lds_read8(lK, row*128 + (cb ^ ((row&7)<<4)));
        #pragma unroll
        for (int q=0;q<8;++q){ float f = bf2f(v[q]); ss += f*f; }
      }
      ss += __shfl_xor(ss, 1, 64);
      ss += __shfl_xor(ss, 2, 64);
      if (part==0) lSq[row] = 0.0625f * ss;
    }
    __syncthreads();
    f32x4 p[16] = {};
    #pragma unroll
    for (int kk=0;kk<2;++kk){
      int kb = (kk*32 + ((lane>>4)<<3))*2;
      int m = w*16 + (lane&15);
      short8 a = lds_read8(lK, m*128 + (kb ^ ((m&7)<<4)));
      #pragma unroll
      for (int ft=0; ft<16; ++ft){
        int n = ft*16 + (lane&15);
        short8 b = lds_read8(lOm, n*128 + (kb ^ ((n&7)<<4)));
        p[ft] = mfma16(a, b, p[ft]);
      }
    }
    float mj[4] = {-1e30f,-1e30f,-1e30f,-1e30f};
    #pragma unroll
    for (int ft=0; ft<16; ++ft)
      #pragma unroll
      for (int j=0;j<4;++j){ float pv = p[ft][j]*SCALE; p[ft][j]=pv; mj[j] = fmaxf(mj[j], pv); }
    #pragma unroll
    for (int j=0;j<4;++j){
      float v = mj[j];
      v = fmaxf(v, __shfl_xor(v,1,64)); v = fmaxf(v, __shfl_xor(v,2,64));
      v = fmaxf(v, __shfl_xor(v,4,64)); v = fmaxf(v, __shfl_xor(v,8,64));
      mj[j] = v;
    }
    float sqv[4];
    #pragma unroll
    for (int j=0;j<4;++j) sqv[j] = lSq[w*16 + ((lane>>4)<<2) + j];
    int llb = w*16 + ((lane>>4)<<2);
    #pragma unroll
    for (int ft=0; ft<16; ++ft){
      int feat = ft*16 + (lane&15);
      float e0, e1, e2, e3;
      {
        e0 = __expf(p[ft][0] - sqv[0] - mj[0]) * INVSQM + EPS_;
        e1 = __expf(p[ft][1] - sqv[1] - mj[1]) * INVSQM + EPS_;
        e2 = __expf(p[ft][2] - sqv[2] - mj[2]) * INVSQM + EPS_;
        e3 = __expf(p[ft][3] - sqv[3] - mj[3]) * INVSQM + EPS_;
      }
      ksa[ft] += (e0 + e1) + (e2 + e3);
      u32x2 pk; pk[0] = cvtpk(e0, e1); pk[1] = cvtpk(e2, e3);
      *reinterpret_cast<u32x2*>((char*)lP + feat*272 + llb*2) = pk;
    }
    __syncthreads();
    #pragma unroll
    for (int ks2=0; ks2<4; ++ks2){
      int kb = (ks2*32 + ((lane>>4)<<3))*2;
      short8 a[4], b[2];
      #pragma unroll
      for (int i=0;i<4;++i){
        int m = i*16 + (lane&15);
        a[i] = lds_read8(lV, m*256 + (kb ^ ((m&15)<<4)));
      }
      #pragma unroll
      for (int j=0;j<2;++j){
        int n = (2*w+j)*16 + (lane&15);
        b[j] = lds_read8(lP, n*272 + kb);
      }
      #pragma unroll
      for (int i=0;i<4;++i)
        #pragma unroll
        for (int j=0;j<2;++j)
          kv[i][j] = mfma16(a[i], b[j], kv[i][j]);
    }
    __syncthreads();
  }
  float* kvb = kvp + (size_t)bid*64*256;
  #pragma unroll
  for (int i=0;i<4;++i)
    #pragma unroll
    for (int j=0;j<2;++j)
      #pragma unroll
      for (int jj=0;jj<4;++jj){
        int dv = i*16 + ((lane>>4)<<2) + jj;
        int feat = (2*w+j)*16 + (lane&15);
        kvb[dv*256 + feat] = kv[i][j][jj];
      }
  #pragma unroll
  for (int ft=0; ft<16; ++ft){
    float v = ksa[ft];
    v += __shfl_xor(v, 16, 64);
    v += __shfl_xor(v, 32, 64);
    if (lane < 16) lKsP[w][ft*16 + lane] = v;
  }
  __syncthreads();
  if (t < 256){
    float s = 0.f;
    #pragma unroll
    for (int wv=0; wv<8; ++wv) s += lKsP[wv][t];
    ksp[(size_t)bid*256 + t] = s;
  }
}

// ---------------- reduce kv partials -> kvT bf16, ksum fp32 ----------------
__global__ __launch_bounds__(256) void k_red(const float* __restrict__ kvp, const float* __restrict__ ksp,
                                             short* __restrict__ kvb, float* __restrict__ ksum){
  int bid = blockIdx.x;
  int bh = bid >> 3, part = bid & 7;
  int t = threadIdx.x;
  const float* base = kvp + (size_t)bh*8*16384;
  short* ob = kvb + (size_t)bh*16384;
  for (int i=0;i<8;++i){
    int e = part*2048 + i*256 + t;
    float s = 0.f;
    #pragma unroll
    for (int sp2=0; sp2<8; ++sp2) s += base[(size_t)sp2*16384 + e];
    ob[e] = f2bf(s);
  }
  if (part == 0){
    const float* kb = ksp + (size_t)bh*8*256;
    float s2 = 0.f;
    #pragma unroll
    for (int sp2=0; sp2<8; ++sp2) s2 += kb[sp2*256 + t];
    ksum[bh*256 + t] = s2;
  }
}

// ---------------- phi(q) r7 + swizzled LDS (om/Q/kvT); P padded-linear ----------------
__global__ __launch_bounds__(512, 4) void k_phiq(const short* __restrict__ qh, const short* __restrict__ kvb,
                                                 const float* __restrict__ ksum, const short* __restrict__ omega,
                                                 short* __restrict__ attn){
  __shared__ __align__(16) char smem[69632];
  short* bufA = (short*)smem;                  // 32768 B: omega then kvT
  short* bufB = (short*)(smem + 32768);        // 34816 B: Q then P (rows 272B)
  float* lSq  = (float*)(smem + 67584);
  float* lKs  = (float*)(smem + 68096);
  float* lDen = (float*)(smem + 69120);
  const int t = threadIdx.x, w = t>>6, lane = t&63;
  const int bid = blockIdx.x;
  const int bh = bid >> 6, lt = bid & 63;
  const int l0 = lt*128;
  const char* qb = (const char*)(qh + (size_t)bh*L_*DK);
  #pragma unroll
  for (int rnd=0; rnd<4; ++rnd){
    int d = (rnd*512 + t)*16;
    int r = d>>7, po = d&127;
    gl_lds16((const char*)omega + r*128 + (po ^ ((r&7)<<4)), (char*)bufA + rnd*8192 + w*1024);
  }
  #pragma unroll
  for (int rnd=0; rnd<2; ++rnd){
    int d = (rnd*512 + t)*16;
    int r = d>>7, po = d&127;
    gl_lds16(qb + (size_t)(l0+r)*128 + (po ^ ((r&7)<<4)), (char*)bufB + rnd*8192 + w*1024);
  }
  if (t < 256) lKs[t] = ksum[bh*256 + t];
  __syncthreads();
  {
    int row = t >> 2, part = t & 3;
    float ss = 0.f;
    #pragma unroll
    for (int hh=0; hh<2; ++hh){
      int cb = part*32 + hh*16;
      short8 v = lds_read8(bufB, row*128 + (cb ^ ((row&7)<<4)));
      #pragma unroll
      for (int q=0;q<8;++q){ float f = bf2f(v[q]); ss += f*f; }
    }
    ss += __shfl_xor(ss, 1, 64);
    ss += __shfl_xor(ss, 2, 64);
    if (part==0) lSq[row] = 0.0625f * ss;
  }
  __syncthreads();
  f32x4 p[16] = {};
  #pragma unroll
  for (int kk=0;kk<2;++kk){
    int kb = (kk*32 + ((lane>>4)<<3))*2;
    int m = w*16 + (lane&15);
    short8 a = lds_read8(bufB, m*128 + (kb ^ ((m&7)<<4)));
    #pragma unroll
    for (int ft=0; ft<16; ++ft){
      int n = ft*16 + (lane&15);
      short8 b = lds_read8(bufA, n*128 + (kb ^ ((n&7)<<4)));
      p[ft] = mfma16(a, b, p[ft]);
    }
  }
  float mj[4] = {-1e30f,-1e30f,-1e30f,-1e30f};
  #pragma unroll
  for (int ft=0;ft<16;++ft)
    #pragma unroll
    for (int j=0;j<4;++j){ float pv = p[ft][j]*SCALE; p[ft][j]=pv; mj[j]=fmaxf(mj[j],pv); }
  #pragma unroll
  for (int j=0;j<4;++j){
    float v = mj[j];
    v = fmaxf(v,__shfl_xor(v,1,64)); v = fmaxf(v,__shfl_xor(v,2,64));
    v = fmaxf(v,__shfl_xor(v,4,64)); v = fmaxf(v,__shfl_xor(v,8,64));
    mj[j] = v;
  }
  float sqv[4];
  #pragma unroll
  for (int j=0;j<4;++j) sqv[j] = lSq[w*16 + ((lane>>4)<<2) + j];
  __syncthreads();   // done reading omega (bufA) and Q (bufB)
  const char* kvg = (const char*)(kvb + (size_t)bh*16384);
  #pragma unroll
  for (int rnd=0; rnd<4; ++rnd){
    int d = (rnd*512 + t)*16;
    int r = d>>9, po = d&511;
    gl_lds16(kvg + (size_t)r*512 + (po ^ ((r&31)<<4)), (char*)bufA + rnd*8192 + w*1024);
  }
  float dpart[4] = {0.f,0.f,0.f,0.f};
  const int rb = w*16 + ((lane>>4)<<2);
  #pragma unroll
  for (int ft=0;ft<8;++ft){
    int feat = ft*16 + (lane&15);
    float ksf = lKs[feat];
    #pragma unroll
    for (int j=0;j<4;++j){
      float e = __expf(p[ft][j]-sqv[j]-mj[j])*INVSQM + EPS_;
      dpart[j] += e*ksf;
      bufB[(rb+j)*136 + feat] = f2bf(e);
    }
  }
  __syncthreads();   // kvT staged; P pass-1 visible
  f32x4 nc[4] = {};
  #pragma unroll
  for (int ks2=0; ks2<4; ++ks2){
    int kb = (ks2*32 + ((lane>>4)<<3))*2;
    int n = w*16 + (lane&15);
    short8 bfr = lds_read8(bufB, n*272 + kb);
    #pragma unroll
    for (int i=0;i<4;++i){
      int mi = i*16 + (lane&15);
      short8 a = lds_read8(bufA, mi*512 + (kb ^ ((mi&31)<<4)));
      nc[i] = mfma16(a, bfr, nc[i]);
    }
  }
  #pragma unroll
  for (int ft=8;ft<16;++ft){
    int feat = ft*16 + (lane&15);
    float ksf = lKs[feat];
    #pragma unroll
    for (int j=0;j<4;++j){
      float e = __expf(p[ft][j]-sqv[j]-mj[j])*INVSQM + EPS_;
      dpart[j] += e*ksf;
      bufB[(rb+j)*136 + (feat-128)] = f2bf(e);
    }
  }
  #pragma unroll
  for (int j=0;j<4;++j){
    float v = dpart[j];
    v += __shfl_xor(v,1,64); v += __shfl_xor(v,2,64);
    v += __shfl_xor(v,4,64); v += __shfl_xor(v,8,64);
    if ((lane&15)==0) lDen[rb + j] = v;
  }
  #pragma unroll
  for (int ks2=4; ks2<8; ++ks2){
    int kbt = (ks2*32 + ((lane>>4)<<3))*2;
    int n = w*16 + (lane&15);
    short8 bfr = lds_read8(bufB, n*272 + (kbt - 256));
    #pragma unroll
    for (int i=0;i<4;++i){
      int mi = i*16 + (lane&15);
      short8 a = lds_read8(bufA, mi*512 + (kbt ^ ((mi&31)<<4)));
      nc[i] = mfma16(a, bfr, nc[i]);
    }
  }
  const int b = bh >> 3, h = bh & 7;
  const int l = w*16 + (lane&15);
  float rden = 1.0f / (lDen[l] + EPS_);
  #pragma unroll
  for (int i=0;i<4;++i){
    u32x2 ov;
    ov[0] = cvtpk(nc[i][0]*rden, nc[i][1]*rden);
    ov[1] = cvtpk(nc[i][2]*rden, nc[i][3]*rden);
    size_t off = ((size_t)(b*L_ + l0 + l))*DM + h*DK + i*16 + ((lane>>4)<<2);
    *reinterpret_cast<u32x2*>(attn + off) = ov;
  }
}

extern "C" void kernel_launch(void* const* d_in, const int* in_sizes, int n_in,
                              void* d_out, int out_size, void* d_ws, size_t ws_size,
                              hipStream_t stream){
  const float* Q  = (const float*)d_in[0];
  const float* K  = (const float*)d_in[1];
  const float* V  = (const float*)d_in[2];
  const float* Wq = (const float*)d_in[3];
  const float* Wk = (const float*)d_in[4];
  const float* Wv = (const float*)d_in[5];
  const float* Wo = (const float*)d_in[6];
  const float* Om = (const float*)d_in[7];
  char* ws = (char*)d_ws;

  short* wt  = (short*)(ws);                  // 2 MB
  short* omc = (short*)(ws + 2097152);        // 64 KB slot

  k_wt<<<256, 256, 0, stream>>>(Wq, Wk, Wv, Wo, wt);
  k_omc<<<16, 256, 0, stream>>>(Om, omc);

  const size_t MONO_NEED = 120946688ull;      // ~115.3 MB
  if (ws_size >= MONO_NEED){
    short* qh   = (short*)(ws + 2162688);
    short* kh   = (short*)(ws + 35717120);
    short* vT   = (short*)(ws + 69271552);
    float* kvp  = (float*)(ws + 102825984);
    float* ksp  = (float*)(ws + 119603200);
    short* kvb  = (short*)(ws + 119865344);
    float* ksum = (float*)(ws + 120913920);
    short* attn = kh;                         // kh dead after k_phik
    k_gemm3<<<dim3(512,3), 256, 0, stream>>>(Q, K, V, wt, qh, kh, vT, 0);
    k_phik<<<256, 512, 0, stream>>>(kh, vT, omc, kvp, ksp);
    k_red<<<256, 256, 0, stream>>>(kvp, ksp, kvb, ksum);
    k_phiq<<<2048, 512, 0, stream>>>(qh, kvb, ksum, omc, attn);
    k_gemmO<<<1024, 256, 0, stream>>>(attn, wt + 786432, (float*)d_out, 0);
  } else {
    // per-batch tier: ~30.4 MB of workspace
    short* qh   = (short*)(ws + 2162688);
    short* kh   = (short*)(ws + 10551296);
    short* vT   = (short*)(ws + 18939904);
    float* kvp  = (float*)(ws + 27328512);
    float* ksp  = (float*)(ws + 31522816);
    short* kvb  = (short*)(ws + 31588352);
    float* ksum = (float*)(ws + 31850496);
    short* attn = kh;
    for (int b=0; b<4; ++b){
      int rbase = b*8192;
      k_gemm3<<<dim3(128,3), 256, 0, stream>>>(Q, K, V, wt, qh, kh, vT, rbase);
      k_phik<<<64, 512, 0, stream>>>(kh, vT, omc, kvp, ksp);
      k_red<<<64, 256, 0, stream>>>(kvp, ksp, kvb, ksum);
      k_phiq<<<512, 512, 0, stream>>>(qh, kvb, ksum, omc, attn);
      k_gemmO<<<256, 256, 0, stream>>>(attn, wt + 786432,
                                       (float*)d_out + (size_t)b*8192*DM, 0);
    }
  }
}

// Round 21
// 255.068 us; speedup vs baseline: 1.0730x; 1.0730x over previous
//
#include <hip/hip_runtime.h>

typedef unsigned int u32;
typedef __attribute__((ext_vector_type(8))) short short8;
typedef __attribute__((ext_vector_type(4))) short short4v;
typedef __attribute__((ext_vector_type(2))) u32 u32x2;
typedef __attribute__((ext_vector_type(4))) float f32x4;

#define DM 512
#define NH 8
#define DK 64
#define NF 256
#define L_ 8192
#define SCALE 0.35355339059327373f   // 64^-0.25
#define INVSQM 0.0625f               // 256^-0.5
#define EPS_ 1e-6f

__device__ __forceinline__ float bf2f(short s){
  union { u32 u; float f; } x; x.u = ((u32)(unsigned short)s) << 16; return x.f;
}
__device__ __forceinline__ short f2bf(float f){
  union { float f; u32 u; } x; x.f = f;
  u32 r = (x.u + 0x7FFF + ((x.u >> 16) & 1)) >> 16;
  return (short)r;
}
// HW packed convert: 2 fp32 -> 2 bf16 (RTNE) in one VALU op [T12 recipe]
__device__ __forceinline__ u32 cvtpk(float lo, float hi){
  u32 r;
  asm("v_cvt_pk_bf16_f32 %0, %1, %2" : "=v"(r) : "v"(lo), "v"(hi));
  return r;
}

typedef const __attribute__((address_space(1))) u32* gas_t;
typedef __attribute__((address_space(3))) u32* las_t;
__device__ __forceinline__ void gl_lds16(const void* g, void* l){
  __builtin_amdgcn_global_load_lds((gas_t)g, (las_t)l, 16, 0, 0);
}
__device__ __forceinline__ f32x4 mfma16(short8 a, short8 b, f32x4 c){
  return __builtin_amdgcn_mfma_f32_16x16x32_bf16(a, b, c, 0, 0, 0);
}
__device__ __forceinline__ short8 lds_read8(const void* base, int byteoff){
  return *reinterpret_cast<const short8*>((const char*)base + byteoff);
}

// ---------------- transpose 4 fp32 weight matrices -> bf16 Wt[n][k] = W[k][n] ----------------
__global__ __launch_bounds__(256) void k_wt(const float* __restrict__ W0, const float* __restrict__ W1,
                                            const float* __restrict__ W2, const float* __restrict__ W3,
                                            short* __restrict__ Wt){
  int bid = blockIdx.x;              // 4 mats x 64 tiles
  int mat = bid >> 6;
  int tr = (bid >> 3) & 7, tc = bid & 7;
  const float* W = mat==0 ? W0 : mat==1 ? W1 : mat==2 ? W2 : W3;
  short* O = Wt + (size_t)mat*DM*DM;
  __shared__ __align__(16) short tl[64*72];   // rows 144B
  int t = threadIdx.x;
  #pragma unroll
  for (int i=0;i<4;++i){
    int c = i*256 + t;               // 1024 chunks of 4 floats
    int r = c >> 4, cc = c & 15;
    f32x4 v = *reinterpret_cast<const f32x4*>(W + (size_t)(tr*64+r)*DM + tc*64 + cc*4);
    u32x2 o; o[0] = cvtpk(v[0], v[1]); o[1] = cvtpk(v[2], v[3]);
    *reinterpret_cast<u32x2*>((char*)tl + r*144 + cc*8) = o;
  }
  __syncthreads();
  #pragma unroll
  for (int i=0;i<2;++i){
    int c = i*256 + t;
    int n = c >> 3, kc = c & 7;
    short8 v;
    #pragma unroll
    for (int q=0;q<8;++q) v[q] = tl[(kc*8+q)*72 + n];
    *reinterpret_cast<short8*>(O + (size_t)(tc*64+n)*DM + tr*64 + kc*8) = v;
  }
}

// ---------------- omega fp32 -> canonical bf16 ----------------
__global__ __launch_bounds__(256) void k_omc(const float* __restrict__ Om, short* __restrict__ omc){
  int i = blockIdx.x*256 + threadIdx.x;
  f32x4 v = *((const f32x4*)Om + i);
  u32x2 o; o[0] = cvtpk(v[0], v[1]); o[1] = cvtpk(v[2], v[3]);
  *((u32x2*)omc + i) = o;
}

// ---------------- merged QKV projection GEMM (r16 config: separate lC, 67.5KB LDS) ----------
// y=0: Q -> qh (headsplit); y=1: K -> kh (headsplit); y=2: V -> vT ([h][dv][L])
__global__ __launch_bounds__(256) void k_gemm3(const float* __restrict__ Q, const float* __restrict__ K,
                                               const float* __restrict__ V, const short* __restrict__ wt,
                                               short* __restrict__ qh, short* __restrict__ kh,
                                               short* __restrict__ vT, int rbase){
  __shared__ __align__(16) short lA[128*64];
  __shared__ __align__(16) short lB[128*64];
  __shared__ __align__(16) short lC[128*136];
  const int mode = blockIdx.y;
  const float* A = mode==0 ? Q : mode==1 ? K : V;
  const short* Bt = wt + (size_t)mode*DM*DM;
  const int t = threadIdx.x;
  const int w = t >> 6, lane = t & 63;
  const int wr = w >> 1, wc = w & 1;
  // XCD-aware swizzle: the 4 blocks sharing an A-panel land on the same XCD.
  const int bid = blockIdx.x;
  const int bmx = gridDim.x >> 5;
  const int j = bid >> 3;
  const int bm = (bid & 7)*bmx + (j >> 2);
  const int bn = j & 3;
  const int row0 = bm*128, n0 = bn*128;
  f32x4 acc[4][4] = {};
  for (int ks=0; ks<8; ++ks){
    const float* gA32 = A + (size_t)(rbase+row0)*DM + ks*64;
    #pragma unroll
    for (int rnd=0; rnd<8; ++rnd){
      int c = rnd*256 + t;
      int r = c >> 4, cc = c & 15;
      f32x4 v = *reinterpret_cast<const f32x4*>(gA32 + (size_t)r*DM + cc*4);
      u32x2 o; o[0] = cvtpk(v[0], v[1]); o[1] = cvtpk(v[2], v[3]);
      int po = cc*8;
      *reinterpret_cast<u32x2*>((char*)lA + r*128 + (po ^ ((r&7)<<4))) = o;
    }
    const char* gB = (const char*)(Bt + (size_t)n0*DM + ks*64);
    #pragma unroll
    for (int rnd=0; rnd<4; ++rnd){
      int d = (rnd*256 + t)*16;
      int r = d >> 7, po = d & 127;
      gl_lds16(gB + (size_t)r*(DM*2) + (po ^ ((r&7)<<4)), (char*)lB + rnd*4096 + w*1024);
    }
    __syncthreads();
    #pragma unroll
    for (int kk=0; kk<2; ++kk){
      int kb = (kk*32 + ((lane>>4)<<3))*2;
      short8 af[4], bfr[4];
      #pragma unroll
      for (int i=0;i<4;++i){
        int m = wr*64 + i*16 + (lane&15);
        af[i] = lds_read8(lA, m*128 + (kb ^ ((m&7)<<4)));
      }
      #pragma unroll
      for (int j2=0;j2<4;++j2){
        int n = wc*64 + j2*16 + (lane&15);
        bfr[j2] = lds_read8(lB, n*128 + (kb ^ ((n&7)<<4)));
      }
      #pragma unroll
      for (int i=0;i<4;++i)
        #pragma unroll
        for (int j2=0;j2<4;++j2)
          acc[i][j2] = mfma16(af[i], bfr[j2], acc[i][j2]);
    }
    __syncthreads();
  }
  #pragma unroll
  for (int i=0;i<4;++i)
    #pragma unroll
    for (int j2=0;j2<4;++j2)
      #pragma unroll
      for (int jj=0;jj<4;++jj){
        int row = wr*64 + i*16 + ((lane>>4)<<2) + jj;
        int col = wc*64 + j2*16 + (lane&15);
        lC[row*136 + col] = f2bf(acc[i][j2][jj]);
      }
  __syncthreads();
  const int b = row0 >> 13;
  const int l0 = row0 & 8191;
  if (mode < 2){
    short* Os = mode ? kh : qh;
    #pragma unroll
    for (int it=0; it<8; ++it){
      int p = it*256 + t;
      int row = p >> 4, c16 = p & 15;
      short8 v = *reinterpret_cast<const short8*>((char*)lC + row*272 + c16*16);
      int col0 = n0 + c16*8;
      int h = col0 >> 6, dv = col0 & 63;
      size_t off = ((size_t)(b*NH + h)*L_ + (l0+row))*DK + dv;
      *reinterpret_cast<short8*>(Os + off) = v;
    }
  } else {
    #pragma unroll
    for (int it=0; it<8; ++it){
      int p = it*256 + t;
      int col = p >> 4, lp = p & 15;
      short8 v;
      #pragma unroll
      for (int q=0;q<8;++q) v[q] = lC[(lp*8+q)*136 + col];
      int h = (n0+col) >> 6, dv = (n0+col) & 63;
      size_t off = ((size_t)(b*NH+h)*DK + dv)*L_ + l0 + lp*8;
      *reinterpret_cast<short8*>(vT + off) = v;
    }
  }
}

// ---------------- output GEMM: attn bf16 [rows,512] x WoT -> fp32 d_out ----------------
__global__ __launch_bounds__(256) void k_gemmO(const short* __restrict__ A, const short* __restrict__ Bt,
                                               float* __restrict__ Out, int rbase){
  __shared__ __align__(16) short lA[128*64];
  __shared__ __align__(16) short lB[128*64];
  const int t = threadIdx.x;
  const int w = t >> 6, lane = t & 63;
  const int wr = w >> 1, wc = w & 1;
  const int bid = blockIdx.x;
  const int bmx = gridDim.x >> 5;
  const int j = bid >> 3;
  const int bm = (bid & 7)*bmx + (j >> 2);
  const int bn = j & 3;
  const int row0 = bm*128, n0 = bn*128;
  f32x4 acc[4][4] = {};
  for (int ks=0; ks<8; ++ks){
    const char* gA = (const char*)(A + (size_t)(rbase+row0)*DM + ks*64);
    #pragma unroll
    for (int rnd=0; rnd<4; ++rnd){
      int d = (rnd*256 + t)*16;
      int r = d >> 7, po = d & 127;
      gl_lds16(gA + (size_t)r*(DM*2) + (po ^ ((r&7)<<4)), (char*)lA + rnd*4096 + w*1024);
    }
    const char* gB = (const char*)(Bt + (size_t)n0*DM + ks*64);
    #pragma unroll
    for (int rnd=0; rnd<4; ++rnd){
      int d = (rnd*256 + t)*16;
      int r = d >> 7, po = d & 127;
      gl_lds16(gB + (size_t)r*(DM*2) + (po ^ ((r&7)<<4)), (char*)lB + rnd*4096 + w*1024);
    }
    __syncthreads();
    #pragma unroll
    for (int kk=0; kk<2; ++kk){
      int kb = (kk*32 + ((lane>>4)<<3))*2;
      short8 af[4], bfr[4];
      #pragma unroll
      for (int i=0;i<4;++i){
        int m = wr*64 + i*16 + (lane&15);
        af[i] = lds_read8(lA, m*128 + (kb ^ ((m&7)<<4)));
      }
      #pragma unroll
      for (int j2=0;j2<4;++j2){
        int n = wc*64 + j2*16 + (lane&15);
        bfr[j2] = lds_read8(lB, n*128 + (kb ^ ((n&7)<<4)));
      }
      #pragma unroll
      for (int i=0;i<4;++i)
        #pragma unroll
        for (int j2=0;j2<4;++j2)
          acc[i][j2] = mfma16(af[i], bfr[j2], acc[i][j2]);
    }
    __syncthreads();
  }
  #pragma unroll
  for (int i=0;i<4;++i)
    #pragma unroll
    for (int j2=0;j2<4;++j2)
      #pragma unroll
      for (int jj=0;jj<4;++jj){
        int row = wr*64 + i*16 + ((lane>>4)<<2) + jj;
        int col = wc*64 + j2*16 + (lane&15);
        Out[(size_t)(row0+row)*DM + n0 + col] = acc[i][j2][jj];
      }
}

// ---------------- phi(k) r7 + swizzled LDS (lOm/lK/lV); lP padded-linear ----------------
// grid = nbh*8 (bh*8+split); 512 threads; each split: 1024 rows = 8 chunks of 128
__global__ __launch_bounds__(512) void k_phik(const short* __restrict__ kh, const short* __restrict__ vT,
                                              const short* __restrict__ omega,
                                              float* __restrict__ kvp, float* __restrict__ ksp){
  __shared__ __align__(16) short lOm[256*64];
  __shared__ __align__(16) short lK[128*64];
  __shared__ __align__(16) short lV[64*128];
  __shared__ __align__(16) short lP[256*136];
  __shared__ float lSq[128];
  __shared__ float lKsP[8][256];
  const int t = threadIdx.x, w = t>>6, lane = t&63;
  const int bid = blockIdx.x;
  const int bh = bid >> 3, sp = bid & 7;
  const char* khb = (const char*)(kh + (size_t)bh*L_*DK);
  const char* vtb = (const char*)(vT + (size_t)bh*DK*L_);
  #pragma unroll
  for (int rnd=0; rnd<4; ++rnd){
    int d = (rnd*512 + t)*16;
    int r = d >> 7, po = d & 127;
    gl_lds16((const char*)omega + r*128 + (po ^ ((r&7)<<4)), (char*)lOm + rnd*8192 + w*1024);
  }
  f32x4 kv[4][2] = {};
  float ksa[16] = {};
  for (int c=0;c<8;++c){
    int l0 = sp*1024 + c*128;
    #pragma unroll
    for (int rnd=0; rnd<2; ++rnd){
      int d = (rnd*512 + t)*16;
      { int r = d>>7, po = d&127;
        gl_lds16(khb + (size_t)(l0+r)*128 + (po ^ ((r&7)<<4)), (char*)lK + rnd*8192 + w*1024); }
      { int r = d>>8, po = d&255;
        gl_lds16(vtb + (size_t)r*(L_*2) + (size_t)l0*2 + (po ^ ((r&15)<<4)), (char*)lV + rnd*8192 + w*1024); }
    }
    __syncthreads();
    {
      int row = t >> 2, part = t & 3;
      float ss = 0.f;
      #pragma unroll
      for (int hh=0; hh<2; ++hh){
        int cb = part*32 + hh*16;
        short8 v = lds_read8(lK, row*128 + (cb ^ ((row&7)<<4)));
        #pragma unroll
        for (int q=0;q<8;++q){ float f = bf2f(v[q]); ss += f*f; }
      }
      ss += __shfl_xor(ss, 1, 64);
      ss += __shfl_xor(ss, 2, 64);
      if (part==0) lSq[row] = 0.0625f * ss;
    }
    __syncthreads();
    f32x4 p[16] = {};
    #pragma unroll
    for (int kk=0;kk<2;++kk){
      int kb = (kk*32 + ((lane>>4)<<3))*2;
      int m = w*16 + (lane&15);
      short8 a = lds_read8(lK, m*128 + (kb ^ ((m&7)<<4)));
      #pragma unroll
      for (int ft=0; ft<16; ++ft){
        int n = ft*16 + (lane&15);
        short8 b = lds_read8(lOm, n*128 + (kb ^ ((n&7)<<4)));
        p[ft] = mfma16(a, b, p[ft]);
      }
    }
    float mj[4] = {-1e30f,-1e30f,-1e30f,-1e30f};
    #pragma unroll
    for (int ft=0; ft<16; ++ft)
      #pragma unroll
      for (int j=0;j<4;++j){ float pv = p[ft][j]*SCALE; p[ft][j]=pv; mj[j] = fmaxf(mj[j], pv); }
    #pragma unroll
    for (int j=0;j<4;++j){
      float v = mj[j];
      v = fmaxf(v, __shfl_xor(v,1,64)); v = fmaxf(v, __shfl_xor(v,2,64));
      v = fmaxf(v, __shfl_xor(v,4,64)); v = fmaxf(v, __shfl_xor(v,8,64));
      mj[j] = v;
    }
    float sqv[4];
    #pragma unroll
    for (int j=0;j<4;++j) sqv[j] = lSq[w*16 + ((lane>>4)<<2) + j];
    int llb = w*16 + ((lane>>4)<<2);
    #pragma unroll
    for (int ft=0; ft<16; ++ft){
      int feat = ft*16 + (lane&15);
      float e0, e1, e2, e3;
      {
        e0 = __expf(p[ft][0] - sqv[0] - mj[0]) * INVSQM + EPS_;
        e1 = __expf(p[ft][1] - sqv[1] - mj[1]) * INVSQM + EPS_;
        e2 = __expf(p[ft][2] - sqv[2] - mj[2]) * INVSQM + EPS_;
        e3 = __expf(p[ft][3] - sqv[3] - mj[3]) * INVSQM + EPS_;
      }
      ksa[ft] += (e0 + e1) + (e2 + e3);
      u32x2 pk; pk[0] = cvtpk(e0, e1); pk[1] = cvtpk(e2, e3);
      *reinterpret_cast<u32x2*>((char*)lP + feat*272 + llb*2) = pk;
    }
    __syncthreads();
    #pragma unroll
    for (int ks2=0; ks2<4; ++ks2){
      int kb = (ks2*32 + ((lane>>4)<<3))*2;
      short8 a[4], b[2];
      #pragma unroll
      for (int i=0;i<4;++i){
        int m = i*16 + (lane&15);
        a[i] = lds_read8(lV, m*256 + (kb ^ ((m&15)<<4)));
      }
      #pragma unroll
      for (int j=0;j<2;++j){
        int n = (2*w+j)*16 + (lane&15);
        b[j] = lds_read8(lP, n*272 + kb);
      }
      #pragma unroll
      for (int i=0;i<4;++i)
        #pragma unroll
        for (int j=0;j<2;++j)
          kv[i][j] = mfma16(a[i], b[j], kv[i][j]);
    }
    __syncthreads();
  }
  float* kvb = kvp + (size_t)bid*64*256;
  #pragma unroll
  for (int i=0;i<4;++i)
    #pragma unroll
    for (int j=0;j<2;++j)
      #pragma unroll
      for (int jj=0;jj<4;++jj){
        int dv = i*16 + ((lane>>4)<<2) + jj;
        int feat = (2*w+j)*16 + (lane&15);
        kvb[dv*256 + feat] = kv[i][j][jj];
      }
  #pragma unroll
  for (int ft=0; ft<16; ++ft){
    float v = ksa[ft];
    v += __shfl_xor(v, 16, 64);
    v += __shfl_xor(v, 32, 64);
    if (lane < 16) lKsP[w][ft*16 + lane] = v;
  }
  __syncthreads();
  if (t < 256){
    float s = 0.f;
    #pragma unroll
    for (int wv=0; wv<8; ++wv) s += lKsP[wv][t];
    ksp[(size_t)bid*256 + t] = s;
  }
}

// ---------------- reduce kv partials -> kvT bf16, ksum fp32 ----------------
__global__ __launch_bounds__(256) void k_red(const float* __restrict__ kvp, const float* __restrict__ ksp,
                                             short* __restrict__ kvb, float* __restrict__ ksum){
  int bid = blockIdx.x;
  int bh = bid >> 3, part = bid & 7;
  int t = threadIdx.x;
  const float* base = kvp + (size_t)bh*8*16384;
  short* ob = kvb + (size_t)bh*16384;
  for (int i=0;i<8;++i){
    int e = part*2048 + i*256 + t;
    float s = 0.f;
    #pragma unroll
    for (int sp2=0; sp2<8; ++sp2) s += base[(size_t)sp2*16384 + e];
    ob[e] = f2bf(s);
  }
  if (part == 0){
    const float* kb = ksp + (size_t)bh*8*256;
    float s2 = 0.f;
    #pragma unroll
    for (int sp2=0; sp2<8; ++sp2) s2 += kb[sp2*256 + t];
    ksum[bh*256 + t] = s2;
  }
}

// ---------------- phi(q) r7 + swizzled LDS (om/Q/kvT); P padded-linear ----------------
__global__ __launch_bounds__(512, 4) void k_phiq(const short* __restrict__ qh, const short* __restrict__ kvb,
                                                 const float* __restrict__ ksum, const short* __restrict__ omega,
                                                 short* __restrict__ attn){
  __shared__ __align__(16) char smem[69632];
  short* bufA = (short*)smem;                  // 32768 B: omega then kvT
  short* bufB = (short*)(smem + 32768);        // 34816 B: Q then P (rows 272B)
  float* lSq  = (float*)(smem + 67584);
  float* lKs  = (float*)(smem + 68096);
  float* lDen = (float*)(smem + 69120);
  const int t = threadIdx.x, w = t>>6, lane = t&63;
  const int bid = blockIdx.x;
  const int bh = bid >> 6, lt = bid & 63;
  const int l0 = lt*128;
  const char* qb = (const char*)(qh + (size_t)bh*L_*DK);
  #pragma unroll
  for (int rnd=0; rnd<4; ++rnd){
    int d = (rnd*512 + t)*16;
    int r = d>>7, po = d&127;
    gl_lds16((const char*)omega + r*128 + (po ^ ((r&7)<<4)), (char*)bufA + rnd*8192 + w*1024);
  }
  #pragma unroll
  for (int rnd=0; rnd<2; ++rnd){
    int d = (rnd*512 + t)*16;
    int r = d>>7, po = d&127;
    gl_lds16(qb + (size_t)(l0+r)*128 + (po ^ ((r&7)<<4)), (char*)bufB + rnd*8192 + w*1024);
  }
  if (t < 256) lKs[t] = ksum[bh*256 + t];
  __syncthreads();
  {
    int row = t >> 2, part = t & 3;
    float ss = 0.f;
    #pragma unroll
    for (int hh=0; hh<2; ++hh){
      int cb = part*32 + hh*16;
      short8 v = lds_read8(bufB, row*128 + (cb ^ ((row&7)<<4)));
      #pragma unroll
      for (int q=0;q<8;++q){ float f = bf2f(v[q]); ss += f*f; }
    }
    ss += __shfl_xor(ss, 1, 64);
    ss += __shfl_xor(ss, 2, 64);
    if (part==0) lSq[row] = 0.0625f * ss;
  }
  __syncthreads();
  f32x4 p[16] = {};
  #pragma unroll
  for (int kk=0;kk<2;++kk){
    int kb = (kk*32 + ((lane>>4)<<3))*2;
    int m = w*16 + (lane&15);
    short8 a = lds_read8(bufB, m*128 + (kb ^ ((m&7)<<4)));
    #pragma unroll
    for (int ft=0; ft<16; ++ft){
      int n = ft*16 + (lane&15);
      short8 b = lds_read8(bufA, n*128 + (kb ^ ((n&7)<<4)));
      p[ft] = mfma16(a, b, p[ft]);
    }
  }
  float mj[4] = {-1e30f,-1e30f,-1e30f,-1e30f};
  #pragma unroll
  for (int ft=0;ft<16;++ft)
    #pragma unroll
    for (int j=0;j<4;++j){ float pv = p[ft][j]*SCALE; p[ft][j]=pv; mj[j]=fmaxf(mj[j],pv); }
  #pragma unroll
  for (int j=0;j<4;++j){
    float v = mj[j];
    v = fmaxf(v,__shfl_xor(v,1,64)); v = fmaxf(v,__shfl_xor(v,2,64));
    v = fmaxf(v,__shfl_xor(v,4,64)); v = fmaxf(v,__shfl_xor(v,8,64));
    mj[j] = v;
  }
  float sqv[4];
  #pragma unroll
  for (int j=0;j<4;++j) sqv[j] = lSq[w*16 + ((lane>>4)<<2) + j];
  __syncthreads();   // done reading omega (bufA) and Q (bufB)
  const char* kvg = (const char*)(kvb + (size_t)bh*16384);
  #pragma unroll
  for (int rnd=0; rnd<4; ++rnd){
    int d = (rnd*512 + t)*16;
    int r = d>>9, po = d&511;
    gl_lds16(kvg + (size_t)r*512 + (po ^ ((r&31)<<4)), (char*)bufA + rnd*8192 + w*1024);
  }
  float dpart[4] = {0.f,0.f,0.f,0.f};
  const int rb = w*16 + ((lane>>4)<<2);
  #pragma unroll
  for (int ft=0;ft<8;++ft){
    int feat = ft*16 + (lane&15);
    float ksf = lKs[feat];
    #pragma unroll
    for (int j=0;j<4;++j){
      float e = __expf(p[ft][j]-sqv[j]-mj[j])*INVSQM + EPS_;
      dpart[j] += e*ksf;
      bufB[(rb+j)*136 + feat] = f2bf(e);
    }
  }
  __syncthreads();   // kvT staged; P pass-1 visible
  f32x4 nc[4] = {};
  #pragma unroll
  for (int ks2=0; ks2<4; ++ks2){
    int kb = (ks2*32 + ((lane>>4)<<3))*2;
    int n = w*16 + (lane&15);
    short8 bfr = lds_read8(bufB, n*272 + kb);
    #pragma unroll
    for (int i=0;i<4;++i){
      int mi = i*16 + (lane&15);
      short8 a = lds_read8(bufA, mi*512 + (kb ^ ((mi&31)<<4)));
      nc[i] = mfma16(a, bfr, nc[i]);
    }
  }
  #pragma unroll
  for (int ft=8;ft<16;++ft){
    int feat = ft*16 + (lane&15);
    float ksf = lKs[feat];
    #pragma unroll
    for (int j=0;j<4;++j){
      float e = __expf(p[ft][j]-sqv[j]-mj[j])*INVSQM + EPS_;
      dpart[j] += e*ksf;
      bufB[(rb+j)*136 + (feat-128)] = f2bf(e);
    }
  }
  #pragma unroll
  for (int j=0;j<4;++j){
    float v = dpart[j];
    v += __shfl_xor(v,1,64); v += __shfl_xor(v,2,64);
    v += __shfl_xor(v,4,64); v += __shfl_xor(v,8,64);
    if ((lane&15)==0) lDen[rb + j] = v;
  }
  #pragma unroll
  for (int ks2=4; ks2<8; ++ks2){
    int kbt = (ks2*32 + ((lane>>4)<<3))*2;
    int n = w*16 + (lane&15);
    short8 bfr = lds_read8(bufB, n*272 + (kbt - 256));
    #pragma unroll
    for (int i=0;i<4;++i){
      int mi = i*16 + (lane&15);
      short8 a = lds_read8(bufA, mi*512 + (kbt ^ ((mi&31)<<4)));
      nc[i] = mfma16(a, bfr, nc[i]);
    }
  }
  const int b = bh >> 3, h = bh & 7;
  const int l = w*16 + (lane&15);
  float rden = 1.0f / (lDen[l] + EPS_);
  #pragma unroll
  for (int i=0;i<4;++i){
    u32x2 ov;
    ov[0] = cvtpk(nc[i][0]*rden, nc[i][1]*rden);
    ov[1] = cvtpk(nc[i][2]*rden, nc[i][3]*rden);
    size_t off = ((size_t)(b*L_ + l0 + l))*DM + h*DK + i*16 + ((lane>>4)<<2);
    *reinterpret_cast<u32x2*>(attn + off) = ov;
  }
}

extern "C" void kernel_launch(void* const* d_in, const int* in_sizes, int n_in,
                              void* d_out, int out_size, void* d_ws, size_t ws_size,
                              hipStream_t stream){
  const float* Q  = (const float*)d_in[0];
  const float* K  = (const float*)d_in[1];
  const float* V  = (const float*)d_in[2];
  const float* Wq = (const float*)d_in[3];
  const float* Wk = (const float*)d_in[4];
  const float* Wv = (const float*)d_in[5];
  const float* Wo = (const float*)d_in[6];
  const float* Om = (const float*)d_in[7];
  char* ws = (char*)d_ws;

  short* wt  = (short*)(ws);                  // 2 MB
  short* omc = (short*)(ws + 2097152);        // 64 KB slot

  k_wt<<<256, 256, 0, stream>>>(Wq, Wk, Wv, Wo, wt);
  k_omc<<<16, 256, 0, stream>>>(Om, omc);

  const size_t MONO_NEED = 120946688ull;      // ~115.3 MB
  if (ws_size >= MONO_NEED){
    short* qh   = (short*)(ws + 2162688);
    short* kh   = (short*)(ws + 35717120);
    short* vT   = (short*)(ws + 69271552);
    float* kvp  = (float*)(ws + 102825984);
    float* ksp  = (float*)(ws + 119603200);
    short* kvb  = (short*)(ws + 119865344);
    float* ksum = (float*)(ws + 120913920);
    short* attn = kh;                         // kh dead after k_phik
    k_gemm3<<<dim3(1024,3), 256, 0, stream>>>(Q, K, V, wt, qh, kh, vT, 0);
    k_phik<<<256, 512, 0, stream>>>(kh, vT, omc, kvp, ksp);
    k_red<<<256, 256, 0, stream>>>(kvp, ksp, kvb, ksum);
    k_phiq<<<2048, 512, 0, stream>>>(qh, kvb, ksum, omc, attn);
    k_gemmO<<<1024, 256, 0, stream>>>(attn, wt + 786432, (float*)d_out, 0);
  } else {
    // per-batch tier: ~30.4 MB of workspace
    short* qh   = (short*)(ws + 2162688);
    short* kh   = (short*)(ws + 10551296);
    short* vT   = (short*)(ws + 18939904);
    float* kvp  = (float*)(ws + 27328512);
    float* ksp  = (float*)(ws + 31522816);
    short* kvb  = (short*)(ws + 31588352);
    float* ksum = (float*)(ws + 31850496);
    short* attn = kh;
    for (int b=0; b<4; ++b){
      int rbase = b*8192;
      k_gemm3<<<dim3(256,3), 256, 0, stream>>>(Q, K, V, wt, qh, kh, vT, rbase);
      k_phik<<<64, 512, 0, stream>>>(kh, vT, omc, kvp, ksp);
      k_red<<<64, 256, 0, stream>>>(kvp, ksp, kvb, ksum);
      k_phiq<<<512, 512, 0, stream>>>(qh, kvb, ksum, omc, attn);
      k_gemmO<<<256, 256, 0, stream>>>(attn, wt + 786432,
                                       (float*)d_out + (size_t)b*8192*DM, 0);
    }
  }
}